// Round 3
// baseline (234.081 us; speedup 1.0000x reference)
//
#include <hip/hip_runtime.h>

typedef __attribute__((ext_vector_type(4))) float f32x4;
typedef __attribute__((ext_vector_type(8))) short bf16x8;

#define D_MODEL 1024
#define NQK     2048   // q cols (0..1023, pre-scaled) + k cols (1024..2047)
#define LSEQ    2048
#define NB      4

__device__ inline unsigned short f2bf(float f) {
  unsigned u = __float_as_uint(f);
  unsigned r = (u + 0x7FFFu + ((u >> 16) & 1u)) >> 16;
  return (unsigned short)r;
}

__device__ inline float bf2f(unsigned short v) {
  return __uint_as_float(((unsigned)v) << 16);
}

__device__ inline void gl_lds16(const void* g, void* l) {
  __builtin_amdgcn_global_load_lds((const __attribute__((address_space(1))) void*)g,
                                   (__attribute__((address_space(3))) void*)l, 16, 0, 0);
}

// ---------------- fp32 -> bf16 convert (vectorized) ----------------
__global__ __launch_bounds__(256) void f32_to_bf16_kernel(
    const float4* __restrict__ src, ushort4* __restrict__ dst) {
  int i = blockIdx.x * 256 + threadIdx.x;
  float4 v = src[i];
  ushort4 o;
  o.x = f2bf(v.x); o.y = f2bf(v.y); o.z = f2bf(v.z); o.w = f2bf(v.w);
  dst[i] = o;
}

// ---------------- GEMM: C[m][n] = sum_k Xb[m][k]*Wb[n][k]; +bias, q-scale, bf16 store ----------------
__global__ __launch_bounds__(256) void gemm_qk(
    const unsigned short* __restrict__ Xb,   // [8192][1024] bf16
    const unsigned short* __restrict__ Wb,   // [2048][1024] bf16
    const float* __restrict__ bias,          // [3072]
    unsigned short* __restrict__ C)          // [8192][2048] bf16
{
  __shared__ unsigned short As[128 * 32];  // 8KB
  __shared__ unsigned short Bs[128 * 32];  // 8KB
  int t = threadIdx.x;
  int w = t >> 6, lane = t & 63;
  int l15 = lane & 15, lg = lane >> 4;
  int m0 = blockIdx.y * 128, n0 = blockIdx.x * 128;
  int wm = (w >> 1) * 64, wn = (w & 1) * 64;
  f32x4 acc[4][4] = {};

  for (int kt = 0; kt < D_MODEL / 32; ++kt) {
#pragma unroll
    for (int i = 0; i < 2; ++i) {
      int ob = w * 1024 + i * 4096;        // wave-uniform LDS base
      int o = ob + lane * 16;              // this lane's slot
      int row = o >> 6;
      int kb = (o & 63) ^ (((row >> 1) & 3) << 4);   // inverse-swizzled source
      gl_lds16(Xb + (m0 + row) * D_MODEL + kt * 32 + (kb >> 1), (char*)As + ob);
      gl_lds16(Wb + (n0 + row) * D_MODEL + kt * 32 + (kb >> 1), (char*)Bs + ob);
    }
    __syncthreads();
    bf16x8 a[4], b[4];
#pragma unroll
    for (int mi = 0; mi < 4; mi++) {
      int row = wm + mi * 16 + l15;
      int kb = (lg * 16) ^ (((row >> 1) & 3) << 4);
      a[mi] = *(const bf16x8*)((const char*)As + row * 64 + kb);
    }
#pragma unroll
    for (int ni = 0; ni < 4; ni++) {
      int row = wn + ni * 16 + l15;
      int kb = (lg * 16) ^ (((row >> 1) & 3) << 4);
      b[ni] = *(const bf16x8*)((const char*)Bs + row * 64 + kb);
    }
#pragma unroll
    for (int mi = 0; mi < 4; mi++)
#pragma unroll
      for (int ni = 0; ni < 4; ni++)
        acc[mi][ni] = __builtin_amdgcn_mfma_f32_16x16x32_bf16(a[mi], b[ni], acc[mi][ni], 0, 0, 0);
    __syncthreads();
  }

#pragma unroll
  for (int ni = 0; ni < 4; ni++) {
    int n = n0 + wn + ni * 16 + l15;
    float bv = bias[n];
    float scale = (n < 1024) ? 0.0625f : 1.0f;   // fold 1/sqrt(hd) into Q
#pragma unroll
    for (int mi = 0; mi < 4; mi++) {
      int mbase = m0 + wm + mi * 16 + lg * 4;
#pragma unroll
      for (int r = 0; r < 4; r++) {
        float v = (acc[mi][ni][r] + bv) * scale;
        C[(mbase + r) * NQK + n] = f2bf(v);
      }
    }
  }
}

// ---------------- fused attention column sums: one QK^T pass, E in registers ----------------
// wg = 512 threads (8 waves). Each wg: one (b,h), 32 query rows, full 2048 keys.
// Wave w handles key strip [w*256, (w+1)*256). E = exp(S) slab lives in VGPRs.
__global__ __launch_bounds__(512) void attn_fused(
    const unsigned short* __restrict__ C,  // [8192][2048] bf16
    float* __restrict__ colsum)            // [4][2048]
{
  __shared__ float Zp[8][32];              // per-wave row-Z partials
  int t = threadIdx.x;
  int w = t >> 6, lane = t & 63;
  int l15 = lane & 15, lg = lane >> 4;

  // XCD swizzle: 128 consecutive nids (2 bh) per XCD -> K slice L2-resident
  int nid = (blockIdx.x & 7) * 128 + (blockIdx.x >> 3);
  int bh = nid >> 6, rb = nid & 63;
  int b = bh >> 2, h = bh & 3;

  const unsigned short* Qbase = C + (size_t)(b * LSEQ + rb * 32) * NQK + h * 256;
  const unsigned short* Kbase = C + (size_t)(b * LSEQ + w * 256) * NQK + 1024 + h * 256;

  // Q fragments: 32 rows x 256 hd, held in registers (A-operand layout)
  bf16x8 qf[2][8];
#pragma unroll
  for (int mi = 0; mi < 2; mi++)
#pragma unroll
    for (int kk = 0; kk < 8; kk++)
      qf[mi][kk] = *(const bf16x8*)(Qbase + (mi * 16 + l15) * NQK + kk * 32 + lg * 8);

  float zacc[2][4] = {};
  unsigned int E[16][2][2];   // exp(S) packed bf16x2, fragment-native order

#pragma unroll
  for (int n = 0; n < 16; n++) {
    bf16x8 kf[8];
#pragma unroll
    for (int kk = 0; kk < 8; kk++)
      kf[kk] = *(const bf16x8*)(Kbase + (n * 16 + l15) * NQK + kk * 32 + lg * 8);
    f32x4 acc[2] = {};
#pragma unroll
    for (int kk = 0; kk < 8; kk++) {
      acc[0] = __builtin_amdgcn_mfma_f32_16x16x32_bf16(qf[0][kk], kf[kk], acc[0], 0, 0, 0);
      acc[1] = __builtin_amdgcn_mfma_f32_16x16x32_bf16(qf[1][kk], kf[kk], acc[1], 0, 0, 0);
    }
#pragma unroll
    for (int mi = 0; mi < 2; mi++) {
      float e0 = __expf(acc[mi][0]);
      float e1 = __expf(acc[mi][1]);
      float e2 = __expf(acc[mi][2]);
      float e3 = __expf(acc[mi][3]);
      zacc[mi][0] += e0; zacc[mi][1] += e1;
      zacc[mi][2] += e2; zacc[mi][3] += e3;
      E[n][mi][0] = (unsigned)f2bf(e0) | ((unsigned)f2bf(e1) << 16);
      E[n][mi][1] = (unsigned)f2bf(e2) | ((unsigned)f2bf(e3) << 16);
    }
  }

  // row-Z: reduce over l15 lanes (same row, different key cols)
#pragma unroll
  for (int mi = 0; mi < 2; mi++)
#pragma unroll
    for (int r = 0; r < 4; r++) {
      float z = zacc[mi][r];
      z += __shfl_xor(z, 1, 64);
      z += __shfl_xor(z, 2, 64);
      z += __shfl_xor(z, 4, 64);
      z += __shfl_xor(z, 8, 64);
      if (l15 == 0) Zp[w][mi * 16 + lg * 4 + r] = z;
    }
  __syncthreads();

  // combine across the 8 key-strip waves -> invZ per row
  float invz[2][4];
#pragma unroll
  for (int mi = 0; mi < 2; mi++) {
    float4 s = make_float4(0.f, 0.f, 0.f, 0.f);
#pragma unroll
    for (int w2 = 0; w2 < 8; w2++) {
      float4 p = *(const float4*)&Zp[w2][mi * 16 + lg * 4];
      s.x += p.x; s.y += p.y; s.z += p.z; s.w += p.w;
    }
    invz[mi][0] = 1.0f / s.x; invz[mi][1] = 1.0f / s.y;
    invz[mi][2] = 1.0f / s.z; invz[mi][3] = 1.0f / s.w;
  }

  // column sums straight from register-resident E
#pragma unroll
  for (int n = 0; n < 16; n++) {
    float c = 0.f;
#pragma unroll
    for (int mi = 0; mi < 2; mi++) {
      c += bf2f((unsigned short)(E[n][mi][0] & 0xFFFF)) * invz[mi][0];
      c += bf2f((unsigned short)(E[n][mi][0] >> 16))    * invz[mi][1];
      c += bf2f((unsigned short)(E[n][mi][1] & 0xFFFF)) * invz[mi][2];
      c += bf2f((unsigned short)(E[n][mi][1] >> 16))    * invz[mi][3];
    }
    c += __shfl_xor(c, 16, 64);
    c += __shfl_xor(c, 32, 64);
    if (lane < 16)
      atomicAdd(&colsum[b * LSEQ + w * 256 + n * 16 + l15], c);
  }
}

// ---------------- zero + finalize ----------------
__global__ __launch_bounds__(256) void zero_kernel(float* __restrict__ p, int n) {
  int i = blockIdx.x * 256 + threadIdx.x;
  if (i < n) p[i] = 0.f;
}

__global__ __launch_bounds__(256) void finalize_kernel(
    const float* __restrict__ colsum, float* __restrict__ out) {
  __shared__ float red[256];
  int t = threadIdx.x;
  float acc = 0.f;
  for (int i = t; i < NB * LSEQ; i += 256) {
    float aw = colsum[i] * (1.0f / 8192.0f) + 1e-8f;
    acc += -aw * __logf(aw);
  }
  red[t] = acc;
  __syncthreads();
  for (int s = 128; s > 0; s >>= 1) {
    if (t < s) red[t] += red[t + s];
    __syncthreads();
  }
  if (t == 0) {
    float me = red[0] * 0.25f;
    out[0] = 1.0f / (1.0f + __expf(-me));
  }
}

extern "C" void kernel_launch(void* const* d_in, const int* in_sizes, int n_in,
                              void* d_out, int out_size, void* d_ws, size_t ws_size,
                              hipStream_t stream) {
  const float* hs   = (const float*)d_in[0];   // [4,2048,1024]
  const float* wgt  = (const float*)d_in[1];   // [3072,1024]
  const float* bias = (const float*)d_in[2];   // [3072]
  float* out = (float*)d_out;
  char* ws = (char*)d_ws;

  unsigned short* Xb  = (unsigned short*)(ws);                        // 16 MB
  unsigned short* Wb  = (unsigned short*)(ws + (16u << 20));          // 4 MB
  unsigned short* Cqk = (unsigned short*)(ws + (20u << 20));          // 32 MB
  float* colsum = (float*)(ws + (54u << 20));                         // 32 KB

  f32_to_bf16_kernel<<<8192, 256, 0, stream>>>((const float4*)hs, (ushort4*)Xb);
  f32_to_bf16_kernel<<<2048, 256, 0, stream>>>((const float4*)wgt, (ushort4*)Wb);

  dim3 g1(16, 64);
  gemm_qk<<<g1, 256, 0, stream>>>(Xb, Wb, bias, Cqk);

  zero_kernel<<<32, 256, 0, stream>>>(colsum, NB * LSEQ);
  attn_fused<<<1024, 512, 0, stream>>>(Cqk, colsum);
  finalize_kernel<<<1, 256, 0, stream>>>(colsum, out);
}

// Round 4
// 166.503 us; speedup vs baseline: 1.4059x; 1.4059x over previous
//
#include <hip/hip_runtime.h>

typedef __attribute__((ext_vector_type(4))) float f32x4;
typedef __attribute__((ext_vector_type(8))) short bf16x8;

#define D_MODEL 1024
#define NQK     2048   // q cols (0..1023, pre-scaled) + k cols (1024..2047)
#define LSEQ    2048
#define NB      4

__device__ inline unsigned short f2bf(float f) {
  unsigned u = __float_as_uint(f);
  unsigned r = (u + 0x7FFFu + ((u >> 16) & 1u)) >> 16;
  return (unsigned short)r;
}

__device__ inline float bf2f(unsigned short v) {
  return __uint_as_float(((unsigned)v) << 16);
}

__device__ inline void gl_lds16(const void* g, void* l) {
  __builtin_amdgcn_global_load_lds((const __attribute__((address_space(1))) void*)g,
                                   (__attribute__((address_space(3))) void*)l, 16, 0, 0);
}

// ---------------- fp32 -> bf16 convert (vectorized) ----------------
__global__ __launch_bounds__(256) void f32_to_bf16_kernel(
    const float4* __restrict__ src, ushort4* __restrict__ dst) {
  int i = blockIdx.x * 256 + threadIdx.x;
  float4 v = src[i];
  ushort4 o;
  o.x = f2bf(v.x); o.y = f2bf(v.y); o.z = f2bf(v.z); o.w = f2bf(v.w);
  dst[i] = o;
}

// ---------------- GEMM: C[m][n] = sum_k Xb[m][k]*Wb[n][k]; +bias, q-scale, bf16 store ----------------
__global__ __launch_bounds__(256) void gemm_qk(
    const unsigned short* __restrict__ Xb,   // [8192][1024] bf16
    const unsigned short* __restrict__ Wb,   // [2048][1024] bf16
    const float* __restrict__ bias,          // [3072]
    unsigned short* __restrict__ C)          // [8192][2048] bf16
{
  __shared__ unsigned short As[128 * 32];  // 8KB
  __shared__ unsigned short Bs[128 * 32];  // 8KB
  int t = threadIdx.x;
  int w = t >> 6, lane = t & 63;
  int l15 = lane & 15, lg = lane >> 4;
  int m0 = blockIdx.y * 128, n0 = blockIdx.x * 128;
  int wm = (w >> 1) * 64, wn = (w & 1) * 64;
  f32x4 acc[4][4] = {};

  for (int kt = 0; kt < D_MODEL / 32; ++kt) {
#pragma unroll
    for (int i = 0; i < 2; ++i) {
      int ob = w * 1024 + i * 4096;        // wave-uniform LDS base
      int o = ob + lane * 16;              // this lane's slot
      int row = o >> 6;
      int kb = (o & 63) ^ (((row >> 1) & 3) << 4);   // inverse-swizzled source
      gl_lds16(Xb + (m0 + row) * D_MODEL + kt * 32 + (kb >> 1), (char*)As + ob);
      gl_lds16(Wb + (n0 + row) * D_MODEL + kt * 32 + (kb >> 1), (char*)Bs + ob);
    }
    __syncthreads();
    bf16x8 a[4], b[4];
#pragma unroll
    for (int mi = 0; mi < 4; mi++) {
      int row = wm + mi * 16 + l15;
      int kb = (lg * 16) ^ (((row >> 1) & 3) << 4);
      a[mi] = *(const bf16x8*)((const char*)As + row * 64 + kb);
    }
#pragma unroll
    for (int ni = 0; ni < 4; ni++) {
      int row = wn + ni * 16 + l15;
      int kb = (lg * 16) ^ (((row >> 1) & 3) << 4);
      b[ni] = *(const bf16x8*)((const char*)Bs + row * 64 + kb);
    }
#pragma unroll
    for (int mi = 0; mi < 4; mi++)
#pragma unroll
      for (int ni = 0; ni < 4; ni++)
        acc[mi][ni] = __builtin_amdgcn_mfma_f32_16x16x32_bf16(a[mi], b[ni], acc[mi][ni], 0, 0, 0);
    __syncthreads();
  }

#pragma unroll
  for (int ni = 0; ni < 4; ni++) {
    int n = n0 + wn + ni * 16 + l15;
    float bv = bias[n];
    float scale = (n < 1024) ? 0.0625f : 1.0f;   // fold 1/sqrt(hd) into Q
#pragma unroll
    for (int mi = 0; mi < 4; mi++) {
      int mbase = m0 + wm + mi * 16 + lg * 4;
#pragma unroll
      for (int r = 0; r < 4; r++) {
        float v = (acc[mi][ni][r] + bv) * scale;
        C[(mbase + r) * NQK + n] = f2bf(v);
      }
    }
  }
}

// ---------------- fused attention column sums: one QK^T pass, E in registers ----------------
// wg = 512 threads (8 waves). Each wg: one (b,h), 32 query rows, full 2048 keys.
// Wave w owns key strip [w*256, (w+1)*256), staged tile-by-tile (16 keys) through a
// wave-private 8KB LDS slice. No barriers in the main loop.
__global__ __launch_bounds__(512) void attn_fused(
    const unsigned short* __restrict__ C,  // [8192][2048] bf16
    float* __restrict__ colsum)            // [4][2048]
{
  __shared__ unsigned short Ks[32768];     // 64KB: 8 waves x 8KB private slices
  int t = threadIdx.x;
  int w = t >> 6, lane = t & 63;
  int l15 = lane & 15, lg = lane >> 4;

  // XCD swizzle: 128 consecutive nids (2 bh) per XCD -> K slice L2-resident
  int nid = (blockIdx.x & 7) * 128 + (blockIdx.x >> 3);
  int bh = nid >> 6, rb = nid & 63;
  int b = bh >> 2, h = bh & 3;

  const unsigned short* Qbase = C + (size_t)(b * LSEQ + rb * 32) * NQK + h * 256;
  const unsigned short* Kbase = C + (size_t)(b * LSEQ + w * 256) * NQK + 1024 + h * 256;
  char* myK = (char*)Ks + w * 8192;

  // Q fragments: 32 rows x 256 hd, held in registers (A-operand layout)
  bf16x8 qf[2][8];
#pragma unroll
  for (int mi = 0; mi < 2; mi++)
#pragma unroll
    for (int kk = 0; kk < 8; kk++)
      qf[mi][kk] = *(const bf16x8*)(Qbase + (mi * 16 + l15) * NQK + kk * 32 + lg * 8);

  float zacc[2][4] = {};
  unsigned int E[16][2][2];   // exp(S) packed bf16x2, fragment-native order

  int swz_rd = (l15 & 7) << 4;

#pragma unroll
  for (int n = 0; n < 16; n++) {
    // stage this wave's 16-key x 256-hd tile (8KB) into its private LDS slice,
    // XOR-swizzled via pre-swizzled global source
    if (n > 0) {
      asm volatile("s_waitcnt lgkmcnt(0)" ::: "memory");  // prior ds_reads done before overwrite
      __builtin_amdgcn_sched_barrier(0);
    }
#pragma unroll
    for (int i = 0; i < 8; i++) {
      int o = i * 1024 + lane * 16;
      int s = o >> 9;
      int db = (o & 511) ^ ((s & 7) << 4);
      gl_lds16(Kbase + (n * 16 + s) * NQK + (db >> 1), myK + o);
    }
    asm volatile("s_waitcnt vmcnt(0)" ::: "memory");
    __builtin_amdgcn_sched_barrier(0);

    f32x4 acc[2] = {};
#pragma unroll
    for (int kk = 0; kk < 8; kk++) {
      bf16x8 kf = *(const bf16x8*)(myK + l15 * 512 + ((kk * 64 + lg * 16) ^ swz_rd));
      acc[0] = __builtin_amdgcn_mfma_f32_16x16x32_bf16(qf[0][kk], kf, acc[0], 0, 0, 0);
      acc[1] = __builtin_amdgcn_mfma_f32_16x16x32_bf16(qf[1][kk], kf, acc[1], 0, 0, 0);
    }
#pragma unroll
    for (int mi = 0; mi < 2; mi++) {
      float e0 = __expf(acc[mi][0]);
      float e1 = __expf(acc[mi][1]);
      float e2 = __expf(acc[mi][2]);
      float e3 = __expf(acc[mi][3]);
      zacc[mi][0] += e0; zacc[mi][1] += e1;
      zacc[mi][2] += e2; zacc[mi][3] += e3;
      E[n][mi][0] = (unsigned)f2bf(e0) | ((unsigned)f2bf(e1) << 16);
      E[n][mi][1] = (unsigned)f2bf(e2) | ((unsigned)f2bf(e3) << 16);
    }
  }

  // all waves done with K before Zp aliases the LDS
  __syncthreads();
  float* Zpf = (float*)Ks;                 // [8][32] per-wave row-Z partials

  // row-Z: reduce over l15 lanes (same row, different key cols)
#pragma unroll
  for (int mi = 0; mi < 2; mi++)
#pragma unroll
    for (int r = 0; r < 4; r++) {
      float z = zacc[mi][r];
      z += __shfl_xor(z, 1, 64);
      z += __shfl_xor(z, 2, 64);
      z += __shfl_xor(z, 4, 64);
      z += __shfl_xor(z, 8, 64);
      if (l15 == 0) Zpf[w * 32 + mi * 16 + lg * 4 + r] = z;
    }
  __syncthreads();

  // combine across the 8 key-strip waves -> invZ per row
  float invz[2][4];
#pragma unroll
  for (int mi = 0; mi < 2; mi++) {
    float4 s = make_float4(0.f, 0.f, 0.f, 0.f);
#pragma unroll
    for (int w2 = 0; w2 < 8; w2++) {
      float4 p = *(const float4*)(Zpf + w2 * 32 + mi * 16 + lg * 4);
      s.x += p.x; s.y += p.y; s.z += p.z; s.w += p.w;
    }
    invz[mi][0] = 1.0f / s.x; invz[mi][1] = 1.0f / s.y;
    invz[mi][2] = 1.0f / s.z; invz[mi][3] = 1.0f / s.w;
  }

  // column sums straight from register-resident E
#pragma unroll
  for (int n = 0; n < 16; n++) {
    float c = 0.f;
#pragma unroll
    for (int mi = 0; mi < 2; mi++) {
      c += bf2f((unsigned short)(E[n][mi][0] & 0xFFFF)) * invz[mi][0];
      c += bf2f((unsigned short)(E[n][mi][0] >> 16))    * invz[mi][1];
      c += bf2f((unsigned short)(E[n][mi][1] & 0xFFFF)) * invz[mi][2];
      c += bf2f((unsigned short)(E[n][mi][1] >> 16))    * invz[mi][3];
    }
    c += __shfl_xor(c, 16, 64);
    c += __shfl_xor(c, 32, 64);
    if (lane < 16)
      atomicAdd(&colsum[b * LSEQ + w * 256 + n * 16 + l15], c);
  }
}

// ---------------- zero + finalize ----------------
__global__ __launch_bounds__(256) void zero_kernel(float* __restrict__ p, int n) {
  int i = blockIdx.x * 256 + threadIdx.x;
  if (i < n) p[i] = 0.f;
}

__global__ __launch_bounds__(256) void finalize_kernel(
    const float* __restrict__ colsum, float* __restrict__ out) {
  __shared__ float red[256];
  int t = threadIdx.x;
  float acc = 0.f;
  for (int i = t; i < NB * LSEQ; i += 256) {
    float aw = colsum[i] * (1.0f / 8192.0f) + 1e-8f;
    acc += -aw * __logf(aw);
  }
  red[t] = acc;
  __syncthreads();
  for (int s = 128; s > 0; s >>= 1) {
    if (t < s) red[t] += red[t + s];
    __syncthreads();
  }
  if (t == 0) {
    float me = red[0] * 0.25f;
    out[0] = 1.0f / (1.0f + __expf(-me));
  }
}

extern "C" void kernel_launch(void* const* d_in, const int* in_sizes, int n_in,
                              void* d_out, int out_size, void* d_ws, size_t ws_size,
                              hipStream_t stream) {
  const float* hs   = (const float*)d_in[0];   // [4,2048,1024]
  const float* wgt  = (const float*)d_in[1];   // [3072,1024]
  const float* bias = (const float*)d_in[2];   // [3072]
  float* out = (float*)d_out;
  char* ws = (char*)d_ws;

  unsigned short* Xb  = (unsigned short*)(ws);                        // 16 MB
  unsigned short* Wb  = (unsigned short*)(ws + (16u << 20));          // 4 MB
  unsigned short* Cqk = (unsigned short*)(ws + (20u << 20));          // 32 MB
  float* colsum = (float*)(ws + (54u << 20));                         // 32 KB

  f32_to_bf16_kernel<<<8192, 256, 0, stream>>>((const float4*)hs, (ushort4*)Xb);
  f32_to_bf16_kernel<<<2048, 256, 0, stream>>>((const float4*)wgt, (ushort4*)Wb);

  dim3 g1(16, 64);
  gemm_qk<<<g1, 256, 0, stream>>>(Xb, Wb, bias, Cqk);

  zero_kernel<<<32, 256, 0, stream>>>(colsum, NB * LSEQ);
  attn_fused<<<1024, 512, 0, stream>>>(Cqk, colsum);
  finalize_kernel<<<1, 256, 0, stream>>>(colsum, out);
}

// Round 5
// 159.186 us; speedup vs baseline: 1.4705x; 1.0460x over previous
//
#include <hip/hip_runtime.h>

typedef __attribute__((ext_vector_type(4))) float f32x4;
typedef __attribute__((ext_vector_type(8))) short bf16x8;

#define D_MODEL 1024
#define NQK     2048   // q cols (0..1023, pre-scaled) + k cols (1024..2047)
#define LSEQ    2048
#define NB      4

__device__ inline unsigned short f2bf(float f) {
  unsigned u = __float_as_uint(f);
  unsigned r = (u + 0x7FFFu + ((u >> 16) & 1u)) >> 16;
  return (unsigned short)r;
}

__device__ inline float bf2f(unsigned short v) {
  return __uint_as_float(((unsigned)v) << 16);
}

__device__ inline void gl_lds16(const void* g, void* l) {
  __builtin_amdgcn_global_load_lds((const __attribute__((address_space(1))) void*)g,
                                   (__attribute__((address_space(3))) void*)l, 16, 0, 0);
}

// ---------------- fp32 -> bf16 convert (vectorized) ----------------
__global__ __launch_bounds__(256) void f32_to_bf16_kernel(
    const float4* __restrict__ src, ushort4* __restrict__ dst) {
  int i = blockIdx.x * 256 + threadIdx.x;
  float4 v = src[i];
  ushort4 o;
  o.x = f2bf(v.x); o.y = f2bf(v.y); o.z = f2bf(v.z); o.w = f2bf(v.w);
  dst[i] = o;
}

// ---------------- GEMM: C[m][n] = sum_k Xb[m][k]*Wb[n][k]; +bias, q-scale, bf16 store ----------------
// 1D grid with bijective XCD swizzle: XCD x owns m-panels [8x, 8x+8) x all 16 n-blocks,
// so the A panel (256KB) + B (4MB) are L2-resident per XCD.
__global__ __launch_bounds__(256) void gemm_qk(
    const unsigned short* __restrict__ Xb,   // [8192][1024] bf16
    const unsigned short* __restrict__ Wb,   // [2048][1024] bf16
    const float* __restrict__ bias,          // [3072]
    unsigned short* __restrict__ C)          // [8192][2048] bf16
{
  __shared__ unsigned short As[128 * 32];  // 8KB
  __shared__ unsigned short Bs[128 * 32];  // 8KB
  int t = threadIdx.x;
  int w = t >> 6, lane = t & 63;
  int l15 = lane & 15, lg = lane >> 4;
  int bid = blockIdx.x;
  int k2 = bid >> 3, xcd = bid & 7;
  int m0 = (xcd * 8 + (k2 >> 4)) * 128;
  int n0 = (k2 & 15) * 128;
  int wm = (w >> 1) * 64, wn = (w & 1) * 64;
  f32x4 acc[4][4] = {};

  for (int kt = 0; kt < D_MODEL / 32; ++kt) {
#pragma unroll
    for (int i = 0; i < 2; ++i) {
      int ob = w * 1024 + i * 4096;        // wave-uniform LDS base
      int o = ob + lane * 16;              // this lane's slot
      int row = o >> 6;
      int kb = (o & 63) ^ (((row >> 1) & 3) << 4);   // inverse-swizzled source
      gl_lds16(Xb + (m0 + row) * D_MODEL + kt * 32 + (kb >> 1), (char*)As + ob);
      gl_lds16(Wb + (n0 + row) * D_MODEL + kt * 32 + (kb >> 1), (char*)Bs + ob);
    }
    __syncthreads();
    bf16x8 a[4], b[4];
#pragma unroll
    for (int mi = 0; mi < 4; mi++) {
      int row = wm + mi * 16 + l15;
      int kb = (lg * 16) ^ (((row >> 1) & 3) << 4);
      a[mi] = *(const bf16x8*)((const char*)As + row * 64 + kb);
    }
#pragma unroll
    for (int ni = 0; ni < 4; ni++) {
      int row = wn + ni * 16 + l15;
      int kb = (lg * 16) ^ (((row >> 1) & 3) << 4);
      b[ni] = *(const bf16x8*)((const char*)Bs + row * 64 + kb);
    }
#pragma unroll
    for (int mi = 0; mi < 4; mi++)
#pragma unroll
      for (int ni = 0; ni < 4; ni++)
        acc[mi][ni] = __builtin_amdgcn_mfma_f32_16x16x32_bf16(a[mi], b[ni], acc[mi][ni], 0, 0, 0);
    __syncthreads();
  }

#pragma unroll
  for (int ni = 0; ni < 4; ni++) {
    int n = n0 + wn + ni * 16 + l15;
    float bv = bias[n];
    float scale = (n < 1024) ? 0.0625f : 1.0f;   // fold 1/sqrt(hd) into Q
#pragma unroll
    for (int mi = 0; mi < 4; mi++) {
      int mbase = m0 + wm + mi * 16 + lg * 4;
#pragma unroll
      for (int r = 0; r < 4; r++) {
        float v = (acc[mi][ni][r] + bv) * scale;
        C[(mbase + r) * NQK + n] = f2bf(v);
      }
    }
  }
}

// ---------------- fused attention column sums: one QK^T pass, E in registers ----------------
// wg = 512 threads (8 waves). Each wg: one (b,h), 32 query rows, full 2048 keys.
// Wave w owns key strip [w*256, (w+1)*256), staged tile-by-tile (16 keys) through a
// wave-private DOUBLE-BUFFERED 2x8KB LDS slice. Counted vmcnt(8) keeps the next
// tile's 8 loads in flight across the current tile's compute. No barriers in loop.
__global__ __launch_bounds__(512) void attn_fused(
    const unsigned short* __restrict__ C,  // [8192][2048] bf16
    float* __restrict__ colsum)            // [4][2048]
{
  __shared__ unsigned short Ks[65536];     // 128KB: 8 waves x (2 x 8KB)
  int t = threadIdx.x;
  int w = t >> 6, lane = t & 63;
  int l15 = lane & 15, lg = lane >> 4;

  // XCD swizzle: 128 consecutive nids (2 bh) per XCD -> K slice L2-resident
  int nid = (blockIdx.x & 7) * 128 + (blockIdx.x >> 3);
  int bh = nid >> 6, rb = nid & 63;
  int b = bh >> 2, h = bh & 3;

  const unsigned short* Qbase = C + (size_t)(b * LSEQ + rb * 32) * NQK + h * 256;
  const unsigned short* Kbase = C + (size_t)(b * LSEQ + w * 256) * NQK + 1024 + h * 256;
  char* buf0 = (char*)Ks + w * 16384;
  char* buf1 = buf0 + 8192;

  // Q fragments: 32 rows x 256 hd, held in registers (A-operand layout)
  bf16x8 qf[2][8];
#pragma unroll
  for (int mi = 0; mi < 2; mi++)
#pragma unroll
    for (int kk = 0; kk < 8; kk++)
      qf[mi][kk] = *(const bf16x8*)(Qbase + (mi * 16 + l15) * NQK + kk * 32 + lg * 8);
  // drain Q loads so manual vmcnt counting below is exact
  asm volatile("s_waitcnt vmcnt(0)" ::: "memory");
  __builtin_amdgcn_sched_barrier(0);

  float zacc[2][4] = {};
  unsigned int E[16][2][2];   // exp(S) packed bf16x2, fragment-native order
  int swz_rd = (l15 & 7) << 4;

  // stage tile n (16 keys x 256 hd = 8KB) into dst, XOR-swizzled via source
#define STAGE(nn, dst)                                                    \
  {                                                                       \
    _Pragma("unroll")                                                     \
    for (int i = 0; i < 8; i++) {                                         \
      int o = i * 1024 + lane * 16;                                       \
      int s = o >> 9;                                                     \
      int db = (o & 511) ^ ((s & 7) << 4);                                \
      gl_lds16(Kbase + ((nn) * 16 + s) * NQK + (db >> 1), (dst) + o);     \
    }                                                                     \
  }

  STAGE(0, buf0);

#pragma unroll
  for (int n = 0; n < 16; n++) {
    char* cur = (n & 1) ? buf1 : buf0;
    char* nxt = (n & 1) ? buf0 : buf1;
    if (n < 15) {
      STAGE(n + 1, nxt);
      asm volatile("s_waitcnt vmcnt(8)" ::: "memory");   // tile n's 8 loads landed
    } else {
      asm volatile("s_waitcnt vmcnt(0)" ::: "memory");
    }
    __builtin_amdgcn_sched_barrier(0);

    f32x4 acc[2] = {};
#pragma unroll
    for (int kk = 0; kk < 8; kk++) {
      bf16x8 kf = *(const bf16x8*)(cur + l15 * 512 + ((kk * 64 + lg * 16) ^ swz_rd));
      acc[0] = __builtin_amdgcn_mfma_f32_16x16x32_bf16(qf[0][kk], kf, acc[0], 0, 0, 0);
      acc[1] = __builtin_amdgcn_mfma_f32_16x16x32_bf16(qf[1][kk], kf, acc[1], 0, 0, 0);
    }
#pragma unroll
    for (int mi = 0; mi < 2; mi++) {
      float e0 = __expf(acc[mi][0]);
      float e1 = __expf(acc[mi][1]);
      float e2 = __expf(acc[mi][2]);
      float e3 = __expf(acc[mi][3]);
      zacc[mi][0] += e0; zacc[mi][1] += e1;
      zacc[mi][2] += e2; zacc[mi][3] += e3;
      E[n][mi][0] = (unsigned)f2bf(e0) | ((unsigned)f2bf(e1) << 16);
      E[n][mi][1] = (unsigned)f2bf(e2) | ((unsigned)f2bf(e3) << 16);
    }
  }
#undef STAGE

  // all waves done with K before Zp aliases the LDS
  __syncthreads();
  float* Zpf = (float*)Ks;                 // [8][32] per-wave row-Z partials

  // row-Z: reduce over l15 lanes (same row, different key cols)
#pragma unroll
  for (int mi = 0; mi < 2; mi++)
#pragma unroll
    for (int r = 0; r < 4; r++) {
      float z = zacc[mi][r];
      z += __shfl_xor(z, 1, 64);
      z += __shfl_xor(z, 2, 64);
      z += __shfl_xor(z, 4, 64);
      z += __shfl_xor(z, 8, 64);
      if (l15 == 0) Zpf[w * 32 + mi * 16 + lg * 4 + r] = z;
    }
  __syncthreads();

  // combine across the 8 key-strip waves -> invZ per row
  float invz[2][4];
#pragma unroll
  for (int mi = 0; mi < 2; mi++) {
    float4 s = make_float4(0.f, 0.f, 0.f, 0.f);
#pragma unroll
    for (int w2 = 0; w2 < 8; w2++) {
      float4 p = *(const float4*)(Zpf + w2 * 32 + mi * 16 + lg * 4);
      s.x += p.x; s.y += p.y; s.z += p.z; s.w += p.w;
    }
    invz[mi][0] = 1.0f / s.x; invz[mi][1] = 1.0f / s.y;
    invz[mi][2] = 1.0f / s.z; invz[mi][3] = 1.0f / s.w;
  }

  // column sums straight from register-resident E
#pragma unroll
  for (int n = 0; n < 16; n++) {
    float c = 0.f;
#pragma unroll
    for (int mi = 0; mi < 2; mi++) {
      c += bf2f((unsigned short)(E[n][mi][0] & 0xFFFF)) * invz[mi][0];
      c += bf2f((unsigned short)(E[n][mi][0] >> 16))    * invz[mi][1];
      c += bf2f((unsigned short)(E[n][mi][1] & 0xFFFF)) * invz[mi][2];
      c += bf2f((unsigned short)(E[n][mi][1] >> 16))    * invz[mi][3];
    }
    c += __shfl_xor(c, 16, 64);
    c += __shfl_xor(c, 32, 64);
    if (lane < 16)
      atomicAdd(&colsum[b * LSEQ + w * 256 + n * 16 + l15], c);
  }
}

// ---------------- zero + finalize ----------------
__global__ __launch_bounds__(256) void zero_kernel(float* __restrict__ p, int n) {
  int i = blockIdx.x * 256 + threadIdx.x;
  if (i < n) p[i] = 0.f;
}

__global__ __launch_bounds__(256) void finalize_kernel(
    const float* __restrict__ colsum, float* __restrict__ out) {
  __shared__ float red[256];
  int t = threadIdx.x;
  float acc = 0.f;
  for (int i = t; i < NB * LSEQ; i += 256) {
    float aw = colsum[i] * (1.0f / 8192.0f) + 1e-8f;
    acc += -aw * __logf(aw);
  }
  red[t] = acc;
  __syncthreads();
  for (int s = 128; s > 0; s >>= 1) {
    if (t < s) red[t] += red[t + s];
    __syncthreads();
  }
  if (t == 0) {
    float me = red[0] * 0.25f;
    out[0] = 1.0f / (1.0f + __expf(-me));
  }
}

extern "C" void kernel_launch(void* const* d_in, const int* in_sizes, int n_in,
                              void* d_out, int out_size, void* d_ws, size_t ws_size,
                              hipStream_t stream) {
  const float* hs   = (const float*)d_in[0];   // [4,2048,1024]
  const float* wgt  = (const float*)d_in[1];   // [3072,1024]
  const float* bias = (const float*)d_in[2];   // [3072]
  float* out = (float*)d_out;
  char* ws = (char*)d_ws;

  unsigned short* Xb  = (unsigned short*)(ws);                        // 16 MB
  unsigned short* Wb  = (unsigned short*)(ws + (16u << 20));          // 4 MB
  unsigned short* Cqk = (unsigned short*)(ws + (20u << 20));          // 32 MB
  float* colsum = (float*)(ws + (54u << 20));                         // 32 KB

  f32_to_bf16_kernel<<<8192, 256, 0, stream>>>((const float4*)hs, (ushort4*)Xb);
  f32_to_bf16_kernel<<<2048, 256, 0, stream>>>((const float4*)wgt, (ushort4*)Wb);

  gemm_qk<<<1024, 256, 0, stream>>>(Xb, Wb, bias, Cqk);

  zero_kernel<<<32, 256, 0, stream>>>(colsum, NB * LSEQ);
  attn_fused<<<1024, 512, 0, stream>>>(Cqk, colsum);
  finalize_kernel<<<1, 256, 0, stream>>>(colsum, out);
}